// Round 6
// baseline (107.633 us; speedup 1.0000x reference)
//
#include <hip/hip_runtime.h>
#include <hip/hip_bf16.h>

typedef __bf16 bf16x8 __attribute__((ext_vector_type(8)));
typedef __bf16 bf16x4 __attribute__((ext_vector_type(4)));
typedef float  f32x4  __attribute__((ext_vector_type(4)));

#define HID   256
#define BM    128
#define PITCH 264   // bf16 elems per LDS row (16B-aligned; 528B stride -> ~2-way banks)

// gate order: 0=ir 1=iz 2=in 3=hz 4=hn
// ---- prepack weights fp32 -> bf16 in MFMA-fragment order --------------------
// fragment (ks,g,cb): lane l, elem j = W_g[cb*16 + (l&15)][ks*32 + (l>>4)*8 + j]
// stored at wb[((ks*5+g)*16+cb)*512 + l*8 + j]  -> each fragment = 1KB contiguous
__global__ void __launch_bounds__(256) prepack_frag(
    const float* __restrict__ w0, const float* __restrict__ w1,
    const float* __restrict__ w2, const float* __restrict__ w3,
    const float* __restrict__ w4, __bf16* __restrict__ wb)
{
    int t    = blockIdx.x * 256 + threadIdx.x;   // 40960 total
    int lane = t & 63;
    int cb   = (t >> 6) & 15;
    int gk   = t >> 10;                          // ks*5 + g
    int g    = gk % 5;
    int ks   = gk / 5;
    const float* W = g == 0 ? w0 : g == 1 ? w1 : g == 2 ? w2 : g == 3 ? w3 : w4;
    int row = cb * 16 + (lane & 15);
    int k0  = ks * 32 + (lane >> 4) * 8;
    float4 p = *(const float4*)(W + row * HID + k0);
    float4 q = *(const float4*)(W + row * HID + k0 + 4);
    bf16x8 o;
    o[0]=(__bf16)p.x; o[1]=(__bf16)p.y; o[2]=(__bf16)p.z; o[3]=(__bf16)p.w;
    o[4]=(__bf16)q.x; o[5]=(__bf16)q.y; o[6]=(__bf16)q.z; o[7]=(__bf16)q.w;
    *(bf16x8*)(wb + (size_t)t * 8) = o;
}

#define MFMA1(D, A_, B_) D = __builtin_amdgcn_mfma_f32_16x16x32_bf16(A_, B_, D, 0, 0, 0)

// 12 MFMAs for row-block mf. Same-acc dependency distance >= 3.
// B_ index: [0..1]=ir [2..3]=iz [4..5]=in [6..7]=hz [8..9]=hn  (g*2+nf)
#define MFMA12(MF, AX, AH, B_) do {                                   \
    _Pragma("unroll")                                                 \
    for (int nf = 0; nf < 2; ++nf) {                                  \
        MFMA1(az[MF][nf],  AX, B_[2 + nf]);                           \
        MFMA1(ar[MF][nf],  AX, B_[0 + nf]);                           \
        MFMA1(anx[MF][nf], AX, B_[4 + nf]);                           \
        MFMA1(az[MF][nf],  AH, B_[6 + nf]);                           \
        MFMA1(ar[MF][nf],  AH, B_[6 + nf]);                           \
        MFMA1(anh[MF][nf], AH, B_[8 + nf]);                           \
    }                                                                 \
} while (0)

// load the 10 B-fragments for K-step KK, colset CS (each a contiguous 1KB burst)
#define LOADB(DST, KK, CS) do {                                       \
    _Pragma("unroll")                                                 \
    for (int g = 0; g < 5; ++g)                                       \
        _Pragma("unroll")                                             \
        for (int nf = 0; nf < 2; ++nf)                                \
            DST[g * 2 + nf] = *(const bf16x8*)(wbase +                \
                (((KK) * 5 + g) * 16 + (CS) * 8 + nf) * 512);         \
} while (0)

// fallback: load fp32 weights JIT and convert (correctness path)
#define LOADB_SLOW(DST, KK, CS) do {                                  \
    _Pragma("unroll")                                                 \
    for (int g = 0; g < 5; ++g)                                       \
        _Pragma("unroll")                                             \
        for (int nf = 0; nf < 2; ++nf) {                              \
            int cb = (CS) * 8 + cg * 2 + nf;                          \
            const float* pp = wsrc[g] + (cb * 16 + lr) * HID + (KK) * 32 + lg * 8; \
            float4 c0 = *(const float4*)(pp), c1 = *(const float4*)(pp + 4); \
            bf16x8 u;                                                 \
            u[0]=(__bf16)c0.x; u[1]=(__bf16)c0.y; u[2]=(__bf16)c0.z; u[3]=(__bf16)c0.w; \
            u[4]=(__bf16)c1.x; u[5]=(__bf16)c1.y; u[6]=(__bf16)c1.z; u[7]=(__bf16)c1.w; \
            DST[g * 2 + nf] = u;                                      \
        }                                                             \
} while (0)

// MFMA cluster for K-step KC with B set B_: mf-major, 2-stage A prefetch
#define CLUSTER(B_, KC) do {                                          \
    const int kb = (KC) * 32 + lg * 8;                                \
    bf16x8 a0x = *(const bf16x8*)(xt + (rbase + 0 * 16 + lr) * PITCH + kb); \
    bf16x8 a0h = *(const bf16x8*)(ht + (rbase + 0 * 16 + lr) * PITCH + kb); \
    bf16x8 a1x = *(const bf16x8*)(xt + (rbase + 1 * 16 + lr) * PITCH + kb); \
    bf16x8 a1h = *(const bf16x8*)(ht + (rbase + 1 * 16 + lr) * PITCH + kb); \
    MFMA12(0, a0x, a0h, B_);                                          \
    a0x = *(const bf16x8*)(xt + (rbase + 2 * 16 + lr) * PITCH + kb);  \
    a0h = *(const bf16x8*)(ht + (rbase + 2 * 16 + lr) * PITCH + kb);  \
    MFMA12(1, a1x, a1h, B_);                                          \
    a1x = *(const bf16x8*)(xt + (rbase + 3 * 16 + lr) * PITCH + kb);  \
    a1h = *(const bf16x8*)(ht + (rbase + 3 * 16 + lr) * PITCH + kb);  \
    MFMA12(2, a0x, a0h, B_);                                          \
    MFMA12(3, a1x, a1h, B_);                                          \
} while (0)

// ---- fused GRU cell ---------------------------------------------------------
// BM=128 rows/block, 8 waves = 2 row-groups x 4 col-groups; two column passes
// (cs=0: cols 0-127, cs=1: cols 128-255). Wave tile per pass: 64 rows x 32 cols.
template<bool PACKED>
__global__ void __launch_bounds__(512, 2) gru_fused(
    const float* __restrict__ x,  const float* __restrict__ h,
    const __bf16* __restrict__ wb,
    const float* __restrict__ w_ir, const float* __restrict__ w_iz,
    const float* __restrict__ w_in, const float* __restrict__ w_hz,
    const float* __restrict__ w_hn,
    const float* __restrict__ b_ir, const float* __restrict__ b_iz,
    const float* __restrict__ b_in, const float* __restrict__ b_hz,
    const float* __restrict__ b_hn,
    float* __restrict__ out)
{
    __shared__ __bf16 xt[BM * PITCH];   // 67.5 KB
    __shared__ __bf16 ht[BM * PITCH];   // 67.5 KB

    const int t    = threadIdx.x;
    const int row0 = blockIdx.x * BM;
    const int lane = t & 63;
    const int wn   = t >> 6;      // 0..7
    const int rg   = wn >> 2;     // row group: rows rg*64 ..
    const int cg   = wn & 3;      // col group: cols cg*32 .. (within colset)
    const int lr   = lane & 15;
    const int lg   = lane >> 4;
    const int rbase = rg * 64;

    const float* wsrc[5] = { w_ir, w_iz, w_in, w_hz, w_hn };
    const __bf16* wbase = wb + cg * 1024 + lane * 8;

    bf16x8 Ba[10], Bb[10];
    if (PACKED) LOADB(Ba, wn, 0);     // first K-step (staggered), colset 0

    // ---- stage x,h tiles (fp32 -> bf16) into LDS, 2 batches of 8 chunks -----
#pragma unroll
    for (int grp = 0; grp < 2; ++grp) {
        float4 vx[8], vh[8];
#pragma unroll
        for (int i = 0; i < 8; ++i) {
            int c = (grp * 8 + i) * 512 + t, r = c >> 6, k4 = (c & 63) * 4;
            vx[i] = *(const float4*)(x + (size_t)(row0 + r) * HID + k4);
            vh[i] = *(const float4*)(h + (size_t)(row0 + r) * HID + k4);
        }
#pragma unroll
        for (int i = 0; i < 8; ++i) {
            int c = (grp * 8 + i) * 512 + t, r = c >> 6, k4 = (c & 63) * 4;
            bf16x4 bx, bh;
            bx[0]=(__bf16)vx[i].x; bx[1]=(__bf16)vx[i].y; bx[2]=(__bf16)vx[i].z; bx[3]=(__bf16)vx[i].w;
            bh[0]=(__bf16)vh[i].x; bh[1]=(__bf16)vh[i].y; bh[2]=(__bf16)vh[i].z; bh[3]=(__bf16)vh[i].w;
            *(bf16x4*)(xt + r * PITCH + k4) = bx;
            *(bf16x4*)(ht + r * PITCH + k4) = bh;
        }
    }
    __syncthreads();

    f32x4 az[4][2], ar[4][2], anx[4][2], anh[4][2];   // 128 accs

#pragma unroll
    for (int cs = 0; cs < 2; ++cs) {
#pragma unroll
        for (int mf = 0; mf < 4; ++mf)
#pragma unroll
            for (int nf = 0; nf < 2; ++nf) {
                az[mf][nf] = (f32x4)0.0f; ar[mf][nf] = (f32x4)0.0f;
                anx[mf][nf] = (f32x4)0.0f; anh[mf][nf] = (f32x4)0.0f;
            }
        if (cs == 1 && PACKED) LOADB(Ba, wn, 1);

        // K loop: 4 pairs of K-steps, static Ba/Bb double-buffer, no copies
#pragma unroll
        for (int i2 = 0; i2 < 4; ++i2) {
            const int kA = (wn + 2 * i2)     & 7;
            const int kB = (wn + 2 * i2 + 1) & 7;
            const int kN = (wn + 2 * i2 + 2) & 7;
            if (PACKED) LOADB(Bb, kB, cs); else LOADB_SLOW(Ba, kA, cs);
            CLUSTER(Ba, kA);
            if (PACKED) {
                if (i2 < 3) LOADB(Ba, kN, cs);
            } else LOADB_SLOW(Bb, kB, cs);
            CLUSTER(Bb, kB);
        }

        // epilogue for this colset: gate fusion, write h_new
        float bz[2], br[2], bnx[2], bnh[2];
#pragma unroll
        for (int nf = 0; nf < 2; ++nf) {
            int col = cs * 128 + cg * 32 + nf * 16 + lr;
            bz[nf]  = b_iz[col] + b_hz[col];
            br[nf]  = b_ir[col] + b_hz[col];
            bnx[nf] = b_in[col];
            bnh[nf] = b_hn[col];
        }
#pragma unroll
        for (int mf = 0; mf < 4; ++mf)
#pragma unroll
            for (int nf = 0; nf < 2; ++nf)
#pragma unroll
                for (int i = 0; i < 4; ++i) {
                    int rl  = rbase + mf * 16 + lg * 4 + i;        // C/D row
                    int col = cs * 128 + cg * 32 + nf * 16 + lr;   // C/D col
                    float z  = 1.0f / (1.0f + __expf(-(az[mf][nf][i] + bz[nf])));
                    float r  = 1.0f / (1.0f + __expf(-(ar[mf][nf][i] + br[nf])));
                    float e2 = __expf(2.0f * (anx[mf][nf][i] + bnx[nf] + r * (anh[mf][nf][i] + bnh[nf])));
                    float g  = 1.0f - 2.0f / (e2 + 1.0f);          // tanh
                    float hp = (float)ht[rl * PITCH + col];
                    out[(size_t)(row0 + rl) * HID + col] = (1.0f - z) * g + z * hp;
                }
    }
}

extern "C" void kernel_launch(void* const* d_in, const int* in_sizes, int n_in,
                              void* d_out, int out_size, void* d_ws, size_t ws_size,
                              hipStream_t stream) {
    const float* x    = (const float*)d_in[0];
    const float* h    = (const float*)d_in[1];
    const float* w_ir = (const float*)d_in[2];
    const float* b_ir = (const float*)d_in[3];
    const float* w_iz = (const float*)d_in[4];
    const float* b_iz = (const float*)d_in[5];
    const float* w_in = (const float*)d_in[6];
    const float* b_in = (const float*)d_in[7];
    const float* w_hz = (const float*)d_in[8];
    const float* b_hz = (const float*)d_in[9];
    const float* w_hn = (const float*)d_in[10];
    const float* b_hn = (const float*)d_in[11];
    float* out = (float*)d_out;

    const int B = in_sizes[0] / HID;                                  // 65536
    const size_t wb_bytes = (size_t)5 * HID * HID * sizeof(__bf16);   // 640 KB

    if (ws_size >= wb_bytes) {
        __bf16* wb = (__bf16*)d_ws;
        prepack_frag<<<160, 256, 0, stream>>>(w_ir, w_iz, w_in, w_hz, w_hn, wb);
        gru_fused<true><<<B / BM, 512, 0, stream>>>(
            x, h, wb, nullptr, nullptr, nullptr, nullptr, nullptr,
            b_ir, b_iz, b_in, b_hz, b_hn, out);
    } else {
        gru_fused<false><<<B / BM, 512, 0, stream>>>(
            x, h, nullptr, w_ir, w_iz, w_in, w_hz, w_hn,
            b_ir, b_iz, b_in, b_hz, b_hn, out);
    }
}

// Round 7
// 97.585 us; speedup vs baseline: 1.1030x; 1.1030x over previous
//
#include <hip/hip_runtime.h>
#include <hip/hip_bf16.h>

typedef __bf16 bf16x8 __attribute__((ext_vector_type(8)));
typedef __bf16 bf16x4 __attribute__((ext_vector_type(4)));
typedef float  f32x4  __attribute__((ext_vector_type(4)));

#define HID   256
#define BM    64
#define PITCH 264   // bf16 elems per LDS row (16B-aligned; 528B row stride -> ~2-way banks)

// gate order: 0=ir 1=iz 2=in 3=hz 4=hn
// ---- prepack weights fp32 -> bf16 in MFMA-fragment order --------------------
// fragment (ks,g,cb): lane l, elem j = W_g[cb*16 + (l&15)][ks*32 + (l>>4)*8 + j]
// stored at wb[((ks*5+g)*16+cb)*512 + l*8 + j]  -> each fragment = 1KB contiguous
__global__ void __launch_bounds__(256) prepack_frag(
    const float* __restrict__ w0, const float* __restrict__ w1,
    const float* __restrict__ w2, const float* __restrict__ w3,
    const float* __restrict__ w4, __bf16* __restrict__ wb)
{
    int t    = blockIdx.x * 256 + threadIdx.x;   // 40960 total
    int lane = t & 63;
    int cb   = (t >> 6) & 15;
    int gk   = t >> 10;                          // ks*5 + g
    int g    = gk % 5;
    int ks   = gk / 5;
    const float* W = g == 0 ? w0 : g == 1 ? w1 : g == 2 ? w2 : g == 3 ? w3 : w4;
    int row = cb * 16 + (lane & 15);
    int k0  = ks * 32 + (lane >> 4) * 8;
    float4 p = *(const float4*)(W + row * HID + k0);
    float4 q = *(const float4*)(W + row * HID + k0 + 4);
    bf16x8 o;
    o[0]=(__bf16)p.x; o[1]=(__bf16)p.y; o[2]=(__bf16)p.z; o[3]=(__bf16)p.w;
    o[4]=(__bf16)q.x; o[5]=(__bf16)q.y; o[6]=(__bf16)q.z; o[7]=(__bf16)q.w;
    *(bf16x8*)(wb + (size_t)t * 8) = o;
}

#define MFMA1(D, A_, B_) D = __builtin_amdgcn_mfma_f32_16x16x32_bf16(A_, B_, D, 0, 0, 0)

// 12 MFMAs for row-block mf using A-frags AX/AH and B set B_
// B_ index: [0..1]=ir [2..3]=iz [4..5]=in [6..7]=hz [8..9]=hn  (g*2+nf)
#define MFMA12(MF, AX, AH, B_) do {                                   \
    _Pragma("unroll")                                                 \
    for (int nf = 0; nf < 2; ++nf) {                                  \
        MFMA1(az[MF][nf],  AX, B_[2 + nf]);                           \
        MFMA1(ar[MF][nf],  AX, B_[0 + nf]);                           \
        MFMA1(anx[MF][nf], AX, B_[4 + nf]);                           \
        MFMA1(az[MF][nf],  AH, B_[6 + nf]);                           \
        MFMA1(ar[MF][nf],  AH, B_[6 + nf]);                           \
        MFMA1(anh[MF][nf], AH, B_[8 + nf]);                           \
    }                                                                 \
} while (0)

// load the 10 B-fragments for K-step KK into DST (each a contiguous 1KB burst)
#define LOADB(DST, KK) do {                                           \
    _Pragma("unroll")                                                 \
    for (int g = 0; g < 5; ++g)                                       \
        _Pragma("unroll")                                             \
        for (int nf = 0; nf < 2; ++nf)                                \
            DST[g * 2 + nf] =                                         \
                *(const bf16x8*)(wbase + ((KK) * 5 + g) * 8192 + nf * 512); \
} while (0)

// fallback: load fp32 weights JIT and convert (correctness path)
#define LOADB_SLOW(DST, KK) do {                                      \
    _Pragma("unroll")                                                 \
    for (int g = 0; g < 5; ++g)                                       \
        _Pragma("unroll")                                             \
        for (int nf = 0; nf < 2; ++nf) {                              \
            const float* pp = wsrc[g] + ((wn * 2 + nf) * 16 + lr) * HID + (KK) * 32 + lg * 8; \
            float4 c0 = *(const float4*)(pp), c1 = *(const float4*)(pp + 4); \
            bf16x8 u;                                                 \
            u[0]=(__bf16)c0.x; u[1]=(__bf16)c0.y; u[2]=(__bf16)c0.z; u[3]=(__bf16)c0.w; \
            u[4]=(__bf16)c1.x; u[5]=(__bf16)c1.y; u[6]=(__bf16)c1.z; u[7]=(__bf16)c1.w; \
            DST[g * 2 + nf] = u;                                      \
        }                                                             \
} while (0)

// MFMA cluster for K-step KC with B set B_: mf-major, 2-stage A prefetch
#define CLUSTER(B_, KC) do {                                          \
    const int kb = (KC) * 32 + lg * 8;                                \
    bf16x8 a0x = *(const bf16x8*)(xt + (0 * 16 + lr) * PITCH + kb);   \
    bf16x8 a0h = *(const bf16x8*)(ht + (0 * 16 + lr) * PITCH + kb);   \
    bf16x8 a1x = *(const bf16x8*)(xt + (1 * 16 + lr) * PITCH + kb);   \
    bf16x8 a1h = *(const bf16x8*)(ht + (1 * 16 + lr) * PITCH + kb);   \
    MFMA12(0, a0x, a0h, B_);                                          \
    a0x = *(const bf16x8*)(xt + (2 * 16 + lr) * PITCH + kb);          \
    a0h = *(const bf16x8*)(ht + (2 * 16 + lr) * PITCH + kb);          \
    MFMA12(1, a1x, a1h, B_);                                          \
    a1x = *(const bf16x8*)(xt + (3 * 16 + lr) * PITCH + kb);          \
    a1h = *(const bf16x8*)(ht + (3 * 16 + lr) * PITCH + kb);          \
    MFMA12(2, a0x, a0h, B_);                                          \
    MFMA12(3, a1x, a1h, B_);                                          \
} while (0)

// ---- fused GRU cell ---------------------------------------------------------
// BM=64 rows/block, 8 waves; wave wn owns all 64 rows x cols [wn*32, wn*32+32)
// R5 skeleton + NONTEMPORAL x/h loads and out stores: keep the streaming
// (zero-reuse) traffic from evicting the 640KB weight pack out of L2.
template<bool PACKED>
__global__ void __launch_bounds__(512, 2) gru_fused(
    const float* __restrict__ x,  const float* __restrict__ h,
    const __bf16* __restrict__ wb,
    const float* __restrict__ w_ir, const float* __restrict__ w_iz,
    const float* __restrict__ w_in, const float* __restrict__ w_hz,
    const float* __restrict__ w_hn,
    const float* __restrict__ b_ir, const float* __restrict__ b_iz,
    const float* __restrict__ b_in, const float* __restrict__ b_hz,
    const float* __restrict__ b_hn,
    float* __restrict__ out)
{
    __shared__ __bf16 xt[BM * PITCH];   // 33 KB
    __shared__ __bf16 ht[BM * PITCH];   // 33 KB

    const int t    = threadIdx.x;
    const int row0 = blockIdx.x * BM;
    const int lane = t & 63;
    const int wn   = t >> 6;      // 0..7 : col slice AND K-start stagger
    const int lr   = lane & 15;
    const int lg   = lane >> 4;

    const float* wsrc[5] = { w_ir, w_iz, w_in, w_hz, w_hn };
    const __bf16* wbase = wb + wn * 1024 + lane * 8;

    // ---- prologue: issue x/h HBM loads (non-temporal), then Ba, then convert
    f32x4 vx[8], vh[8];
#pragma unroll
    for (int i = 0; i < 8; ++i) {
        int c = i * 512 + t, r = c >> 6, k4 = (c & 63) * 4;
        vx[i] = __builtin_nontemporal_load((const f32x4*)(x + (size_t)(row0 + r) * HID + k4));
        vh[i] = __builtin_nontemporal_load((const f32x4*)(h + (size_t)(row0 + r) * HID + k4));
    }
    bf16x8 Ba[10], Bb[10];
    if (PACKED) LOADB(Ba, wn);        // first K-step for this wave (staggered)
#pragma unroll
    for (int i = 0; i < 8; ++i) {
        int c = i * 512 + t, r = c >> 6, k4 = (c & 63) * 4;
        bf16x4 bx, bh;
        bx[0] = (__bf16)vx[i][0]; bx[1] = (__bf16)vx[i][1]; bx[2] = (__bf16)vx[i][2]; bx[3] = (__bf16)vx[i][3];
        bh[0] = (__bf16)vh[i][0]; bh[1] = (__bf16)vh[i][1]; bh[2] = (__bf16)vh[i][2]; bh[3] = (__bf16)vh[i][3];
        *(bf16x4*)(xt + r * PITCH + k4) = bx;
        *(bf16x4*)(ht + r * PITCH + k4) = bh;
    }
    __syncthreads();

    f32x4 az[4][2], ar[4][2], anx[4][2], anh[4][2];   // 128 accs
#pragma unroll
    for (int mf = 0; mf < 4; ++mf)
#pragma unroll
        for (int nf = 0; nf < 2; ++nf) {
            az[mf][nf] = (f32x4)0.0f; ar[mf][nf] = (f32x4)0.0f;
            anx[mf][nf] = (f32x4)0.0f; anh[mf][nf] = (f32x4)0.0f;
        }

    // ---- K loop: 4 x (pair of K-steps), static double-buffer, no copies -----
#pragma unroll
    for (int i2 = 0; i2 < 4; ++i2) {
        const int kA = (wn + 2 * i2)     & 7;
        const int kB = (wn + 2 * i2 + 1) & 7;
        const int kN = (wn + 2 * i2 + 2) & 7;
        if (PACKED) LOADB(Bb, kB); else LOADB_SLOW(Ba, kA);
        CLUSTER(Ba, kA);
        if (PACKED) { if (i2 < 3) LOADB(Ba, kN); } else LOADB_SLOW(Bb, kB);
        CLUSTER(Bb, kB);
    }

    // ---- epilogue: gate fusion, write h_new (non-temporal stores) -----------
    float bz[2], br[2], bnx[2], bnh[2];
#pragma unroll
    for (int nf = 0; nf < 2; ++nf) {
        int col = wn * 32 + nf * 16 + lr;
        bz[nf]  = b_iz[col] + b_hz[col];
        br[nf]  = b_ir[col] + b_hz[col];
        bnx[nf] = b_in[col];
        bnh[nf] = b_hn[col];
    }
#pragma unroll
    for (int mf = 0; mf < 4; ++mf)
#pragma unroll
        for (int nf = 0; nf < 2; ++nf)
#pragma unroll
            for (int i = 0; i < 4; ++i) {
                int rl  = mf * 16 + lg * 4 + i;          // C/D: row=(lane>>4)*4+i
                int col = wn * 32 + nf * 16 + lr;        //      col=lane&15
                float z  = 1.0f / (1.0f + __expf(-(az[mf][nf][i] + bz[nf])));
                float r  = 1.0f / (1.0f + __expf(-(ar[mf][nf][i] + br[nf])));
                float e2 = __expf(2.0f * (anx[mf][nf][i] + bnx[nf] + r * (anh[mf][nf][i] + bnh[nf])));
                float g  = 1.0f - 2.0f / (e2 + 1.0f);    // tanh
                float hp = (float)ht[rl * PITCH + col];
                __builtin_nontemporal_store((1.0f - z) * g + z * hp,
                                            out + (size_t)(row0 + rl) * HID + col);
            }
}

extern "C" void kernel_launch(void* const* d_in, const int* in_sizes, int n_in,
                              void* d_out, int out_size, void* d_ws, size_t ws_size,
                              hipStream_t stream) {
    const float* x    = (const float*)d_in[0];
    const float* h    = (const float*)d_in[1];
    const float* w_ir = (const float*)d_in[2];
    const float* b_ir = (const float*)d_in[3];
    const float* w_iz = (const float*)d_in[4];
    const float* b_iz = (const float*)d_in[5];
    const float* w_in = (const float*)d_in[6];
    const float* b_in = (const float*)d_in[7];
    const float* w_hz = (const float*)d_in[8];
    const float* b_hz = (const float*)d_in[9];
    const float* w_hn = (const float*)d_in[10];
    const float* b_hn = (const float*)d_in[11];
    float* out = (float*)d_out;

    const int B = in_sizes[0] / HID;                                  // 65536
    const size_t wb_bytes = (size_t)5 * HID * HID * sizeof(__bf16);   // 640 KB

    if (ws_size >= wb_bytes) {
        __bf16* wb = (__bf16*)d_ws;
        prepack_frag<<<160, 256, 0, stream>>>(w_ir, w_iz, w_in, w_hz, w_hn, wb);
        gru_fused<true><<<B / BM, 512, 0, stream>>>(
            x, h, wb, nullptr, nullptr, nullptr, nullptr, nullptr,
            b_ir, b_iz, b_in, b_hz, b_hn, out);
    } else {
        gru_fused<false><<<B / BM, 512, 0, stream>>>(
            x, h, nullptr, w_ir, w_iz, w_in, w_hz, w_hn,
            b_ir, b_iz, b_in, b_hz, b_hn, out);
    }
}